// Round 1
// 367.626 us; speedup vs baseline: 1.0750x; 1.0750x over previous
//
#include <hip/hip_runtime.h>
#include <hip/hip_bf16.h>

// Problem constants
#define BATCH 32
#define CIN   1024
#define HW    784     // 28*28
#define WIMG  28
#define PADW  30      // padded 30x30 plane
#define PADHW 900
#define P1    256
#define P2    256
#define P3    1024
#define NFLAT (BATCH * HW)   // 25088 = 196 * 128 exactly

typedef __attribute__((ext_vector_type(8))) short bfrag_t;          // 8 bf16 (4 VGPRs)
typedef __attribute__((ext_vector_type(8))) unsigned short usvec8;
typedef __attribute__((ext_vector_type(4))) float accvec_t;

static __device__ __forceinline__ unsigned short f2bf(float f) {
    union { __hip_bfloat16 h; unsigned short u; } cv;
    cv.h = __float2bfloat16(f);
    return cv.u;
}
static __device__ __forceinline__ float bf2f(unsigned short u) {
    union { float f; unsigned int i; } cv;
    cv.i = ((unsigned int)u) << 16;
    return cv.f;
}

// async 16B global->LDS DMA. LDS dest is wave-uniform base + lane*16B.
#define GLDS16(g, l) __builtin_amdgcn_global_load_lds(                      \
        (const __attribute__((address_space(1))) void*)(g),                 \
        (__attribute__((address_space(3))) void*)(l), 16, 0, 0)

// ---------------- pre-pass: transpose perm_dconv -> permT[p][c] ----------------
__global__ __launch_bounds__(256) void permT_kernel(const int* __restrict__ perm,
                                                    int* __restrict__ permT) {
    int p = blockIdx.x, c = threadIdx.x;
    permT[p * P1 + c] = perm[c * HW + p];
}

// ---------------- pre-pass: pack weights to bf16 ----------------
// w1b[m][k]; w3b[m][k]; wdb[r][m][k] = bf16(wd[m][k][r])
__global__ __launch_bounds__(256) void pack_weights_kernel(
        const float* __restrict__ w1, const float* __restrict__ wd,
        const float* __restrict__ w3, unsigned short* __restrict__ w1b,
        unsigned short* __restrict__ wdb, unsigned short* __restrict__ w3b) {
    int i = blockIdx.x * 256 + threadIdx.x;
    if (i < 262144) w1b[i] = f2bf(w1[i]);
    int i2 = i - 262144;
    if (i2 >= 0 && i2 < 262144) w3b[i2] = f2bf(w3[i2]);
    int i3 = i - 524288;
    if (i3 >= 0 && i3 < 589824) {
        int m = i3 / 2304, rem = i3 - m * 2304;
        int k = rem / 9, r = rem - k * 9;
        wdb[((size_t)r * P2 + m) * P1 + k] = f2bf(wd[i3]);
    }
}

// ---------------- pre-pass: transpose x -> xt[b*HW+hw][c] bf16 ----------------
__global__ __launch_bounds__(256) void transpose_x_kernel(const float* __restrict__ x,
                                                          unsigned short* __restrict__ xt) {
    __shared__ unsigned short T[64 * 66];
    const int b   = blockIdx.z;
    const int c0  = blockIdx.x * 64;
    const int hw0 = blockIdx.y * 64;
    const int t = threadIdx.x;
    const int j = t & 63, i0 = t >> 6;
    const float* xb = x + ((size_t)b * CIN + c0) * HW + hw0;
    const bool jv = (hw0 + j) < HW;
#pragma unroll
    for (int ii = 0; ii < 16; ++ii) {
        int i = i0 * 16 + ii;
        float v = jv ? xb[(size_t)i * HW + j] : 0.f;
        T[i * 66 + j] = f2bf(v);
    }
    __syncthreads();
#pragma unroll
    for (int ii = 0; ii < 16; ++ii) {
        int rr = i0 * 16 + ii;
        if (hw0 + rr < HW)
            xt[((size_t)b * HW + hw0 + rr) * CIN + c0 + j] = T[j * 66 + rr];
    }
}

// ---------------- residual shuffle via LDS: res[b][c][hw] = bf16(x[b][c][perm_res[c][hw]]) ----
__global__ __launch_bounds__(256) void res_shuffle_kernel(const float* __restrict__ x,
                                                          const int* __restrict__ perm_res,
                                                          unsigned short* __restrict__ res) {
    __shared__ float Lx[8 * 788];     // 8 rows, stride 788 (16B-aligned)
    const int g0 = blockIdx.x * 8;    // 8 (b,c) rows per block
    const int t = threadIdx.x;
    // phase 1: coalesced float4 loads of 8 rows (x flat index = g*784)
#pragma unroll
    for (int it = 0; it < 7; ++it) {
        int chunk = it * 256 + t;
        if (chunk < 1568) {
            int r = chunk / 196, off = (chunk - r * 196) * 4;
            float4 v = *(const float4*)&x[(size_t)(g0 + r) * HW + off];
            *(float4*)&Lx[r * 788 + off] = v;
        }
    }
    __syncthreads();
    // phase 2: gather from LDS, coalesced bf16 stores
    const int q0 = t & 63;
#pragma unroll
    for (int rp = 0; rp < 2; ++rp) {
        int r = rp * 4 + (t >> 6);
        int g = g0 + r;
        int m = g & (CIN - 1);
        const int* pr = perm_res + (size_t)m * HW;
#pragma unroll
        for (int it = 0; it < 13; ++it) {
            int q = it * 64 + q0;
            if (q < HW) {
                int pv = pr[q];
                res[(size_t)g * HW + q] = f2bf(Lx[r * 788 + pv]);
            }
        }
    }
}

// ---------------- shuffle+pad via LDS: y1sp[b][pos][c] from y1c[b][c][hw] ----------------
__global__ __launch_bounds__(256) void shuffle_pad_kernel(const unsigned short* __restrict__ y1c,
                                                          const int* __restrict__ permT,
                                                          unsigned short* __restrict__ y1sp) {
    __shared__ unsigned short Ly[32 * 800];   // 32 channels x plane, stride 800 (16B-aligned)
    const int b  = blockIdx.x >> 3;
    const int c0 = (blockIdx.x & 7) * 32;
    const int t = threadIdx.x;
    // phase 1: coalesced 16B loads of 32 channel rows
#pragma unroll
    for (int it = 0; it < 13; ++it) {
        int chunk = it * 256 + t;
        if (chunk < 3136) {
            int c = chunk / 98, off8 = (chunk - c * 98) * 8;
            usvec8 v = *(const usvec8*)&y1c[((size_t)(b * P1 + c0 + c)) * HW + off8];
            *(usvec8*)&Ly[c * 800 + off8] = v;
        }
    }
    __syncthreads();
    // phase 2: per output pos, gather per-channel source, write 64B channel segments
    const int pc = t & 31, pi = t >> 5;   // 32 channels x 8 positions
    unsigned short* yb = y1sp + (size_t)b * PADHW * P1 + c0 + pc;
#pragma unroll 4
    for (int it = 0; it < 98; ++it) {
        int p = it * 8 + pi;
        int pv = permT[p * P1 + c0 + pc];
        unsigned short val = Ly[pc * 800 + pv];
        int ph = p / WIMG, pw = p - ph * WIMG;
        yb[(size_t)((ph + 1) * PADW + pw + 1) * P1] = val;
    }
}

// ======================================================================
// GEMMs: 128x128 tile, 4 waves (2x2), BK=64 with XOR chunk swizzle,
// async global_load_lds (16B). LDS row = 64 ushorts (128B), contiguous.
// ======================================================================

// ---------------- conv1: y1c[b][m][hw] = relu(W1 x X) ----------------
__global__ __launch_bounds__(256) void conv1_kernel(const unsigned short* __restrict__ xt,
                                                    const unsigned short* __restrict__ w1b,
                                                    unsigned short* __restrict__ y1c) {
    __shared__ __align__(16) unsigned short As[128 * 64];
    __shared__ __align__(16) unsigned short Bs[128 * 64];
    const int m0 = blockIdx.x * 128;
    const int n0 = blockIdx.y * 128;
    const int t = threadIdx.x;
    const int lane = t & 63, wave = t >> 6;
    const int l15 = lane & 15, quad = lane >> 4;
    const int wm = wave & 1, wn = wave >> 1;
    // staging: per wave 4 issues x (8 rows x 128B)
    const int grow = lane >> 3;
    const int gsw  = ((lane & 7) ^ grow) << 3;     // swizzled k-chunk (ushort offset)
    const unsigned short* Asrc[4];
    const unsigned short* Bsrc[4];
    int ldso[4];
#pragma unroll
    for (int j = 0; j < 4; ++j) {
        int q = wave * 4 + j;
        int row = (q << 3) + grow;
        Asrc[j] = w1b + (size_t)(m0 + row) * CIN + gsw;
        Bsrc[j] = xt + (size_t)(n0 + row) * CIN + gsw;
        ldso[j] = q * 512;
    }
    const int coff0 = ((quad)     ^ (l15 & 7)) << 3;
    const int coff1 = ((quad + 4) ^ (l15 & 7)) << 3;

    accvec_t acc[4][4];
    const accvec_t zero = {0.f, 0.f, 0.f, 0.f};
#pragma unroll
    for (int i = 0; i < 4; ++i)
#pragma unroll
        for (int j = 0; j < 4; ++j) acc[i][j] = zero;

    for (int k0 = 0; k0 < CIN; k0 += 64) {
#pragma unroll
        for (int j = 0; j < 4; ++j) {
            GLDS16(Asrc[j] + k0, &As[ldso[j]]);
            GLDS16(Bsrc[j] + k0, &Bs[ldso[j]]);
        }
        __syncthreads();
        bfrag_t af[4], bfr[4];
#pragma unroll
        for (int i = 0; i < 4; ++i) {
            af[i]  = *(const bfrag_t*)&As[(wm * 64 + i * 16 + l15) * 64 + coff0];
            bfr[i] = *(const bfrag_t*)&Bs[(wn * 64 + i * 16 + l15) * 64 + coff0];
        }
#pragma unroll
        for (int im = 0; im < 4; ++im)
#pragma unroll
            for (int in = 0; in < 4; ++in)
                acc[im][in] = __builtin_amdgcn_mfma_f32_16x16x32_bf16(af[im], bfr[in], acc[im][in], 0, 0, 0);
#pragma unroll
        for (int i = 0; i < 4; ++i) {
            af[i]  = *(const bfrag_t*)&As[(wm * 64 + i * 16 + l15) * 64 + coff1];
            bfr[i] = *(const bfrag_t*)&Bs[(wn * 64 + i * 16 + l15) * 64 + coff1];
        }
#pragma unroll
        for (int im = 0; im < 4; ++im)
#pragma unroll
            for (int in = 0; in < 4; ++in)
                acc[im][in] = __builtin_amdgcn_mfma_f32_16x16x32_bf16(af[im], bfr[in], acc[im][in], 0, 0, 0);
        __syncthreads();
    }
    // coalesced store: y1c[b][m][hw], hw on l15
#pragma unroll
    for (int in = 0; in < 4; ++in) {
        const int n = n0 + wn * 64 + in * 16 + l15;
        const int b = n / HW, hw = n - b * HW;
#pragma unroll
        for (int im = 0; im < 4; ++im) {
#pragma unroll
            for (int r = 0; r < 4; ++r) {
                const int m = m0 + wm * 64 + im * 16 + (quad << 2) + r;
                float v = acc[im][in][r];
                v = v > 0.f ? v : 0.f;
                y1c[((size_t)(b * P1 + m)) * HW + hw] = f2bf(v);
            }
        }
    }
}

// ---------------- dconv: y2t[n][m] = relu(conv3x3(y1sp, wdb)) ----------------
// operands SWAPPED in mfma so D col(lane&15)=m -> m-contiguous stores
__global__ __launch_bounds__(256) void dconv_kernel(const unsigned short* __restrict__ y1sp,
                                                    const unsigned short* __restrict__ wdb,
                                                    unsigned short* __restrict__ y2t) {
    __shared__ __align__(16) unsigned short As[128 * 64];
    __shared__ __align__(16) unsigned short Bs[128 * 64];
    const int m0 = blockIdx.x * 128;
    const int n0 = blockIdx.y * 128;
    const int t = threadIdx.x;
    const int lane = t & 63, wave = t >> 6;
    const int l15 = lane & 15, quad = lane >> 4;
    const int wm = wave & 1, wn = wave >> 1;
    const int grow = lane >> 3;
    const int gsw  = ((lane & 7) ^ grow) << 3;
    const unsigned short* Asrc[4];
    const unsigned short* Bsrc[4];
    int ldso[4];
#pragma unroll
    for (int j = 0; j < 4; ++j) {
        int q = wave * 4 + j;
        int row = (q << 3) + grow;
        Asrc[j] = wdb + (size_t)(m0 + row) * P1 + gsw;
        int n = n0 + row;
        int b = n / HW, hw = n - b * HW;
        int h = hw / WIMG, w = hw - h * WIMG;
        Bsrc[j] = y1sp + ((size_t)b * PADHW + h * PADW + w) * P1 + gsw;  // top-left of 3x3 window
        ldso[j] = q * 512;
    }
    const int coff0 = ((quad)     ^ (l15 & 7)) << 3;
    const int coff1 = ((quad + 4) ^ (l15 & 7)) << 3;

    accvec_t acc[4][4];
    const accvec_t zero = {0.f, 0.f, 0.f, 0.f};
#pragma unroll
    for (int i = 0; i < 4; ++i)
#pragma unroll
        for (int j = 0; j < 4; ++j) acc[i][j] = zero;

    for (int r = 0; r < 9; ++r) {
        const int kh = r / 3, kw = r - kh * 3;
        const size_t aoff = (size_t)r * (P1 * P2);
        const int taboff = (kh * PADW + kw) * P1;
        for (int k0 = 0; k0 < P1; k0 += 64) {
#pragma unroll
            for (int j = 0; j < 4; ++j) {
                GLDS16(Asrc[j] + aoff + k0, &As[ldso[j]]);
                GLDS16(Bsrc[j] + taboff + k0, &Bs[ldso[j]]);
            }
            __syncthreads();
            bfrag_t af[4], bfr[4];
#pragma unroll
            for (int i = 0; i < 4; ++i) {
                af[i]  = *(const bfrag_t*)&As[(wm * 64 + i * 16 + l15) * 64 + coff0];
                bfr[i] = *(const bfrag_t*)&Bs[(wn * 64 + i * 16 + l15) * 64 + coff0];
            }
#pragma unroll
            for (int im = 0; im < 4; ++im)
#pragma unroll
                for (int in = 0; in < 4; ++in)
                    acc[im][in] = __builtin_amdgcn_mfma_f32_16x16x32_bf16(bfr[in], af[im], acc[im][in], 0, 0, 0);
#pragma unroll
            for (int i = 0; i < 4; ++i) {
                af[i]  = *(const bfrag_t*)&As[(wm * 64 + i * 16 + l15) * 64 + coff1];
                bfr[i] = *(const bfrag_t*)&Bs[(wn * 64 + i * 16 + l15) * 64 + coff1];
            }
#pragma unroll
            for (int im = 0; im < 4; ++im)
#pragma unroll
                for (int in = 0; in < 4; ++in)
                    acc[im][in] = __builtin_amdgcn_mfma_f32_16x16x32_bf16(bfr[in], af[im], acc[im][in], 0, 0, 0);
            __syncthreads();
        }
    }
    // swapped D mapping: col(l15)=m, row(quad*4+r)=n
#pragma unroll
    for (int im = 0; im < 4; ++im) {
        const int m = m0 + wm * 64 + im * 16 + l15;
#pragma unroll
        for (int in = 0; in < 4; ++in) {
#pragma unroll
            for (int r = 0; r < 4; ++r) {
                const int n = n0 + wn * 64 + in * 16 + (quad << 2) + r;
                float v = acc[im][in][r];
                v = v > 0.f ? v : 0.f;
                y2t[(size_t)n * P2 + m] = f2bf(v);
            }
        }
    }
}

// ---------------- conv3 + residual add + relu ----------------
// K-loop identical to previous version (proven). Epilogue rewritten:
// LDS-bounce the 128x128 fp32 tile in 4 chunks of 32x128 so that
//  - out stores are 64B-contiguous per thread (512B per m-row per block,
//    full 128B lines -> no write-allocate over-fetch)
//  - res loads are 16B ushort8 vectors, prefetched one chunk ahead
// Obuf (32 x stride-132 floats = 16.9KB) aliases the As/Bs staging LDS.
__global__ __launch_bounds__(256) void conv3_kernel(const unsigned short* __restrict__ y2t,
                                                    const unsigned short* __restrict__ w3b,
                                                    const unsigned short* __restrict__ res,
                                                    float* __restrict__ out) {
    __shared__ __align__(16) unsigned short SMEM[8448];   // 16.9KB: As(8KB)+Bs(8KB), aliased by Obuf
    unsigned short* As = SMEM;
    unsigned short* Bs = SMEM + 4096;
    float* Obuf = (float*)SMEM;                           // 32 rows x stride 132 floats

    const int m0 = blockIdx.x * 128;
    const int n0 = blockIdx.y * 128;
    const int t = threadIdx.x;
    const int lane = t & 63, wave = t >> 6;
    const int l15 = lane & 15, quad = lane >> 4;
    const int wm = wave & 1, wn = wave >> 1;
    const int srow = lane >> 2, c8 = (lane & 3) << 3;
    const int row0 = wave * 32 + srow, row1 = row0 + 16;

    const unsigned short* a0 = w3b + (size_t)(m0 + row0) * P2 + c8;
    const unsigned short* a1 = w3b + (size_t)(m0 + row1) * P2 + c8;
    const unsigned short* b0 = y2t + (size_t)(n0 + row0) * P2 + c8;
    const unsigned short* b1 = y2t + (size_t)(n0 + row1) * P2 + c8;
    unsigned short* Ad0 = &As[(wave * 2 + 0) * 512];
    unsigned short* Ad1 = &As[(wave * 2 + 1) * 512];
    unsigned short* Bd0 = &Bs[(wave * 2 + 0) * 512];
    unsigned short* Bd1 = &Bs[(wave * 2 + 1) * 512];

    // epilogue geometry (computable up-front): thread t -> (erow, eseg):
    // erow = m-row within 32-row chunk, eseg*16 = n-offset within the 128-n tile.
    // 784 % 16 == 0 and n0 % 128 == 0 -> a 16-n segment never crosses a batch image.
    const int erow = t >> 3, eseg = t & 7;
    const int n_e  = n0 + eseg * 16;
    const int b_e  = n_e / HW;
    const int hw_e = n_e - b_e * HW;
    const size_t ebase0 = ((size_t)(b_e * P3 + m0 + erow)) * HW + hw_e;

    // prefetch chunk-0 residual (16 bf16 = 2 x 16B, 32B-aligned)
    usvec8 rsA = *(const usvec8*)&res[ebase0];
    usvec8 rsB = *(const usvec8*)&res[ebase0 + 8];

    accvec_t acc[4][4];
    const accvec_t zero = {0.f, 0.f, 0.f, 0.f};
#pragma unroll
    for (int i = 0; i < 4; ++i)
#pragma unroll
        for (int j = 0; j < 4; ++j) acc[i][j] = zero;

    for (int k0 = 0; k0 < P2; k0 += 32) {
        GLDS16(a0 + k0, Ad0);
        GLDS16(a1 + k0, Ad1);
        GLDS16(b0 + k0, Bd0);
        GLDS16(b1 + k0, Bd1);
        __syncthreads();
        bfrag_t af[4], bfr[4];
#pragma unroll
        for (int i = 0; i < 4; ++i) {
            af[i]  = *(const bfrag_t*)&As[(wm * 64 + i * 16 + l15) * 32 + (quad << 3)];
            bfr[i] = *(const bfrag_t*)&Bs[(wn * 64 + i * 16 + l15) * 32 + (quad << 3)];
        }
#pragma unroll
        for (int im = 0; im < 4; ++im)
#pragma unroll
            for (int in = 0; in < 4; ++in)
                acc[im][in] = __builtin_amdgcn_mfma_f32_16x16x32_bf16(af[im], bfr[in], acc[im][in], 0, 0, 0);
        __syncthreads();
    }

    // ---- LDS-bounce epilogue: 4 chunks of 32 m-rows x 128 n ----
#pragma unroll
    for (int c = 0; c < 4; ++c) {
        // write phase: the two waves owning this 32-row chunk (wm == c>>1)
        if (wm == (c >> 1)) {
            const int imb = (c & 1) * 2;
#pragma unroll
            for (int i2 = 0; i2 < 2; ++i2)
#pragma unroll
                for (int in = 0; in < 4; ++in)
#pragma unroll
                    for (int r = 0; r < 4; ++r)
                        Obuf[(i2 * 16 + (quad << 2) + r) * 132 + wn * 64 + in * 16 + l15] =
                            acc[imb + i2][in][r];
        }
        __syncthreads();
        // prefetch next chunk's residual while this chunk drains
        usvec8 nxA = rsA, nxB = rsB;
        if (c < 3) {
            const size_t nb = ebase0 + (size_t)(c + 1) * 32 * HW;
            nxA = *(const usvec8*)&res[nb];
            nxB = *(const usvec8*)&res[nb + 8];
        }
        // read phase: all 256 threads; 64B contiguous out per thread
        {
            const size_t base = ebase0 + (size_t)c * 32 * HW;
            float ov[16];
#pragma unroll
            for (int q4 = 0; q4 < 4; ++q4) {
                float4 v = *(const float4*)&Obuf[erow * 132 + eseg * 16 + q4 * 4];
                ov[q4 * 4 + 0] = v.x; ov[q4 * 4 + 1] = v.y;
                ov[q4 * 4 + 2] = v.z; ov[q4 * 4 + 3] = v.w;
            }
#pragma unroll
            for (int q4 = 0; q4 < 4; ++q4) {
                float4 w;
                float e0, e1, e2, e3;
                const int j = q4 * 4;
                e0 = ov[j + 0] + bf2f((unsigned short)(j + 0 < 8 ? rsA[j + 0] : rsB[j + 0 - 8]));
                e1 = ov[j + 1] + bf2f((unsigned short)(j + 1 < 8 ? rsA[j + 1] : rsB[j + 1 - 8]));
                e2 = ov[j + 2] + bf2f((unsigned short)(j + 2 < 8 ? rsA[j + 2] : rsB[j + 2 - 8]));
                e3 = ov[j + 3] + bf2f((unsigned short)(j + 3 < 8 ? rsA[j + 3] : rsB[j + 3 - 8]));
                w.x = e0 > 0.f ? e0 : 0.f;
                w.y = e1 > 0.f ? e1 : 0.f;
                w.z = e2 > 0.f ? e2 : 0.f;
                w.w = e3 > 0.f ? e3 : 0.f;
                *(float4*)&out[base + q4 * 4] = w;
            }
        }
        rsA = nxA; rsB = nxB;
        if (c < 3) __syncthreads();   // protect Obuf before next chunk's write phase
    }
}

extern "C" void kernel_launch(void* const* d_in, const int* in_sizes, int n_in,
                              void* d_out, int out_size, void* d_ws, size_t ws_size,
                              hipStream_t stream) {
    const float* x      = (const float*)d_in[0];
    const float* w1     = (const float*)d_in[1];
    const float* wd     = (const float*)d_in[2];
    const float* w3     = (const float*)d_in[3];
    const int*   perm_d = (const int*)d_in[4];
    const int*   perm_r = (const int*)d_in[5];
    float*       out    = (float*)d_out;

    char* ws = (char*)d_ws;
    unsigned short* y1sp  = (unsigned short*)(ws + 0);         // 14,745,600
    unsigned short* y2t   = (unsigned short*)(ws + 14745600);  // 12,845,056 (also y1c — dconv overwrites after shuffle_pad consumed it)
    int*            permT = (int*)(ws + 27590656);             //    802,816
    unsigned short* w1b   = (unsigned short*)(ws + 28393472);  //    524,288
    unsigned short* wdb   = (unsigned short*)(ws + 28917760);  //  1,179,648
    unsigned short* w3b   = (unsigned short*)(ws + 30097408);  //    524,288
    unsigned short* xt    = (unsigned short*)(ws + 30621696);  // 51,380,224 (also res — res_shuffle overwrites after conv1 consumed it)
    unsigned short* resb  = xt;
    unsigned short* y1c   = y2t;

    hipMemsetAsync(y1sp, 0, (size_t)BATCH * PADHW * P1 * sizeof(unsigned short), stream);
    permT_kernel<<<dim3(HW), dim3(256), 0, stream>>>(perm_d, permT);
    pack_weights_kernel<<<dim3(4352), dim3(256), 0, stream>>>(w1, wd, w3, w1b, wdb, w3b);
    transpose_x_kernel<<<dim3(16, 13, BATCH), dim3(256), 0, stream>>>(x, xt);

    conv1_kernel<<<dim3(P1 / 128, NFLAT / 128), dim3(256), 0, stream>>>(xt, w1b, y1c);
    res_shuffle_kernel<<<dim3(BATCH * CIN / 8), dim3(256), 0, stream>>>(x, perm_r, resb);
    shuffle_pad_kernel<<<dim3(BATCH * 8), dim3(256), 0, stream>>>(y1c, permT, y1sp);
    dconv_kernel<<<dim3(P2 / 128, NFLAT / 128), dim3(256), 0, stream>>>(y1sp, wdb, y2t);
    conv3_kernel<<<dim3(P3 / 128, NFLAT / 128), dim3(256), 0, stream>>>(y2t, w3b, resb, out);
}

// Round 2
// 355.466 us; speedup vs baseline: 1.1118x; 1.0342x over previous
//
#include <hip/hip_runtime.h>
#include <hip/hip_bf16.h>

// Problem constants
#define BATCH 32
#define CIN   1024
#define HW    784     // 28*28
#define WIMG  28
#define PADW  30      // padded 30x30 plane
#define PADHW 900
#define P1    256
#define P2    256
#define P3    1024
#define NFLAT (BATCH * HW)   // 25088 = 196 * 128 = 392 * 64 exactly

typedef __attribute__((ext_vector_type(8))) short bfrag_t;          // 8 bf16 (4 VGPRs)
typedef __attribute__((ext_vector_type(8))) unsigned short usvec8;
typedef __attribute__((ext_vector_type(4))) unsigned short usvec4;
typedef __attribute__((ext_vector_type(4))) float accvec_t;

static __device__ __forceinline__ unsigned short f2bf(float f) {
    union { __hip_bfloat16 h; unsigned short u; } cv;
    cv.h = __float2bfloat16(f);
    return cv.u;
}
static __device__ __forceinline__ float bf2f(unsigned short u) {
    union { float f; unsigned int i; } cv;
    cv.i = ((unsigned int)u) << 16;
    return cv.f;
}

// async 16B global->LDS DMA. LDS dest is wave-uniform base + lane*16B.
#define GLDS16(g, l) __builtin_amdgcn_global_load_lds(                      \
        (const __attribute__((address_space(1))) void*)(g),                 \
        (__attribute__((address_space(3))) void*)(l), 16, 0, 0)

// ---------------- pre-pass: transpose perm_dconv -> permT[p][c] ----------------
__global__ __launch_bounds__(256) void permT_kernel(const int* __restrict__ perm,
                                                    int* __restrict__ permT) {
    int p = blockIdx.x, c = threadIdx.x;
    permT[p * P1 + c] = perm[c * HW + p];
}

// ---------------- pre-pass: pack weights to bf16 ----------------
// w1b[m][k]; w3b[m][k]; wdb[r][m][k] = bf16(wd[m][k][r])
__global__ __launch_bounds__(256) void pack_weights_kernel(
        const float* __restrict__ w1, const float* __restrict__ wd,
        const float* __restrict__ w3, unsigned short* __restrict__ w1b,
        unsigned short* __restrict__ wdb, unsigned short* __restrict__ w3b) {
    int i = blockIdx.x * 256 + threadIdx.x;
    if (i < 262144) w1b[i] = f2bf(w1[i]);
    int i2 = i - 262144;
    if (i2 >= 0 && i2 < 262144) w3b[i2] = f2bf(w3[i2]);
    int i3 = i - 524288;
    if (i3 >= 0 && i3 < 589824) {
        int m = i3 / 2304, rem = i3 - m * 2304;
        int k = rem / 9, r = rem - k * 9;
        wdb[((size_t)r * P2 + m) * P1 + k] = f2bf(wd[i3]);
    }
}

// ---------------- pre-pass: transpose x -> xt[n][c] bf16, n = b*HW+hw ----------------
// Fully vectorized: NFLAT = 392*64 exactly -> no guards.
// Phase 1: lane loads 4x float4 (4 channels x hw-quad), 4x4 reg transpose,
//          4x b64 LDS writes into T[hw][c] (stride 72 ushorts, 16B-aligned rows).
// Phase 2: 2x ds_read_b128 + 2x 16B global stores (128B/8-lane segments).
__global__ __launch_bounds__(256) void transpose_x_kernel(const float* __restrict__ x,
                                                          unsigned short* __restrict__ xt) {
    __shared__ __align__(16) unsigned short T[64 * 72];   // [hw_local][c_local], stride 72
    const int c0 = blockIdx.x * 64;
    const int n0 = blockIdx.y * 64;
    const int t  = threadIdx.x;
    const int f  = t & 15;          // hw-quad index: hw_local = 4f..4f+3
    const int cg = t >> 4;          // channel group: c_local = 4cg..4cg+3
    const int n  = n0 + f * 4;
    const int b  = n / HW, hw = n - b * HW;       // float4 never straddles b (784 % 4 == 0)
    const float* xb = x + ((size_t)b * CIN + c0 + cg * 4) * HW + hw;
    float4 v0 = *(const float4*)&xb[0];
    float4 v1 = *(const float4*)&xb[HW];
    float4 v2 = *(const float4*)&xb[2 * HW];
    float4 v3 = *(const float4*)&xb[3 * HW];
    const float* vr[4] = {(const float*)&v0, (const float*)&v1,
                          (const float*)&v2, (const float*)&v3};
#pragma unroll
    for (int q = 0; q < 4; ++q) {
        usvec4 w;
        w[0] = f2bf(vr[0][q]);
        w[1] = f2bf(vr[1][q]);
        w[2] = f2bf(vr[2][q]);
        w[3] = f2bf(vr[3][q]);
        *(usvec4*)&T[(f * 4 + q) * 72 + cg * 4] = w;
    }
    __syncthreads();
#pragma unroll
    for (int it = 0; it < 2; ++it) {
        int idx  = it * 256 + t;
        int hw_l = idx >> 3, cgo = idx & 7;
        usvec8 w = *(const usvec8*)&T[hw_l * 72 + cgo * 8];
        *(usvec8*)&xt[(size_t)(n0 + hw_l) * CIN + c0 + cgo * 8] = w;
    }
}

// ---------------- residual shuffle via LDS: res[b][c][hw] = bf16(x[b][c][perm_res[c][hw]]) ----
__global__ __launch_bounds__(256) void res_shuffle_kernel(const float* __restrict__ x,
                                                          const int* __restrict__ perm_res,
                                                          unsigned short* __restrict__ res) {
    __shared__ float Lx[8 * 788];     // 8 rows, stride 788 (16B-aligned)
    const int g0 = blockIdx.x * 8;    // 8 (b,c) rows per block
    const int t = threadIdx.x;
    // phase 1: coalesced float4 loads of 8 rows (x flat index = g*784)
#pragma unroll
    for (int it = 0; it < 7; ++it) {
        int chunk = it * 256 + t;
        if (chunk < 1568) {
            int r = chunk / 196, off = (chunk - r * 196) * 4;
            float4 v = *(const float4*)&x[(size_t)(g0 + r) * HW + off];
            *(float4*)&Lx[r * 788 + off] = v;
        }
    }
    __syncthreads();
    // phase 2: gather from LDS, coalesced bf16 stores
    const int q0 = t & 63;
#pragma unroll
    for (int rp = 0; rp < 2; ++rp) {
        int r = rp * 4 + (t >> 6);
        int g = g0 + r;
        int m = g & (CIN - 1);
        const int* pr = perm_res + (size_t)m * HW;
#pragma unroll
        for (int it = 0; it < 13; ++it) {
            int q = it * 64 + q0;
            if (q < HW) {
                int pv = pr[q];
                res[(size_t)g * HW + q] = f2bf(Lx[r * 788 + pv]);
            }
        }
    }
}

// ---------------- shuffle+pad via LDS: y1sp[b][pos][c] from y1c[b][c][hw] ----------------
__global__ __launch_bounds__(256) void shuffle_pad_kernel(const unsigned short* __restrict__ y1c,
                                                          const int* __restrict__ permT,
                                                          unsigned short* __restrict__ y1sp) {
    __shared__ unsigned short Ly[32 * 800];   // 32 channels x plane, stride 800 (16B-aligned)
    const int b  = blockIdx.x >> 3;
    const int c0 = (blockIdx.x & 7) * 32;
    const int t = threadIdx.x;
    // phase 1: coalesced 16B loads of 32 channel rows
#pragma unroll
    for (int it = 0; it < 13; ++it) {
        int chunk = it * 256 + t;
        if (chunk < 3136) {
            int c = chunk / 98, off8 = (chunk - c * 98) * 8;
            usvec8 v = *(const usvec8*)&y1c[((size_t)(b * P1 + c0 + c)) * HW + off8];
            *(usvec8*)&Ly[c * 800 + off8] = v;
        }
    }
    __syncthreads();
    // phase 2: per output pos, gather per-channel source, write 64B channel segments
    const int pc = t & 31, pi = t >> 5;   // 32 channels x 8 positions
    unsigned short* yb = y1sp + (size_t)b * PADHW * P1 + c0 + pc;
#pragma unroll 4
    for (int it = 0; it < 98; ++it) {
        int p = it * 8 + pi;
        int pv = permT[p * P1 + c0 + pc];
        unsigned short val = Ly[pc * 800 + pv];
        int ph = p / WIMG, pw = p - ph * WIMG;
        yb[(size_t)((ph + 1) * PADW + pw + 1) * P1] = val;
    }
}

// ======================================================================
// GEMMs: 128x128 tile, 4 waves (2x2), BK=64 with XOR chunk swizzle,
// async global_load_lds (16B). LDS row = 64 ushorts (128B), contiguous.
// ======================================================================

// ---------------- conv1: y1c[b][m][hw] = relu(W1 x X) ----------------
__global__ __launch_bounds__(256) void conv1_kernel(const unsigned short* __restrict__ xt,
                                                    const unsigned short* __restrict__ w1b,
                                                    unsigned short* __restrict__ y1c) {
    __shared__ __align__(16) unsigned short As[128 * 64];
    __shared__ __align__(16) unsigned short Bs[128 * 64];
    const int m0 = blockIdx.x * 128;
    const int n0 = blockIdx.y * 128;
    const int t = threadIdx.x;
    const int lane = t & 63, wave = t >> 6;
    const int l15 = lane & 15, quad = lane >> 4;
    const int wm = wave & 1, wn = wave >> 1;
    // staging: per wave 4 issues x (8 rows x 128B)
    const int grow = lane >> 3;
    const int gsw  = ((lane & 7) ^ grow) << 3;     // swizzled k-chunk (ushort offset)
    const unsigned short* Asrc[4];
    const unsigned short* Bsrc[4];
    int ldso[4];
#pragma unroll
    for (int j = 0; j < 4; ++j) {
        int q = wave * 4 + j;
        int row = (q << 3) + grow;
        Asrc[j] = w1b + (size_t)(m0 + row) * CIN + gsw;
        Bsrc[j] = xt + (size_t)(n0 + row) * CIN + gsw;
        ldso[j] = q * 512;
    }
    const int coff0 = ((quad)     ^ (l15 & 7)) << 3;
    const int coff1 = ((quad + 4) ^ (l15 & 7)) << 3;

    accvec_t acc[4][4];
    const accvec_t zero = {0.f, 0.f, 0.f, 0.f};
#pragma unroll
    for (int i = 0; i < 4; ++i)
#pragma unroll
        for (int j = 0; j < 4; ++j) acc[i][j] = zero;

    for (int k0 = 0; k0 < CIN; k0 += 64) {
#pragma unroll
        for (int j = 0; j < 4; ++j) {
            GLDS16(Asrc[j] + k0, &As[ldso[j]]);
            GLDS16(Bsrc[j] + k0, &Bs[ldso[j]]);
        }
        __syncthreads();
        bfrag_t af[4], bfr[4];
#pragma unroll
        for (int i = 0; i < 4; ++i) {
            af[i]  = *(const bfrag_t*)&As[(wm * 64 + i * 16 + l15) * 64 + coff0];
            bfr[i] = *(const bfrag_t*)&Bs[(wn * 64 + i * 16 + l15) * 64 + coff0];
        }
#pragma unroll
        for (int im = 0; im < 4; ++im)
#pragma unroll
            for (int in = 0; in < 4; ++in)
                acc[im][in] = __builtin_amdgcn_mfma_f32_16x16x32_bf16(af[im], bfr[in], acc[im][in], 0, 0, 0);
#pragma unroll
        for (int i = 0; i < 4; ++i) {
            af[i]  = *(const bfrag_t*)&As[(wm * 64 + i * 16 + l15) * 64 + coff1];
            bfr[i] = *(const bfrag_t*)&Bs[(wn * 64 + i * 16 + l15) * 64 + coff1];
        }
#pragma unroll
        for (int im = 0; im < 4; ++im)
#pragma unroll
            for (int in = 0; in < 4; ++in)
                acc[im][in] = __builtin_amdgcn_mfma_f32_16x16x32_bf16(af[im], bfr[in], acc[im][in], 0, 0, 0);
        __syncthreads();
    }
    // coalesced store: y1c[b][m][hw], hw on l15
#pragma unroll
    for (int in = 0; in < 4; ++in) {
        const int n = n0 + wn * 64 + in * 16 + l15;
        const int b = n / HW, hw = n - b * HW;
#pragma unroll
        for (int im = 0; im < 4; ++im) {
#pragma unroll
            for (int r = 0; r < 4; ++r) {
                const int m = m0 + wm * 64 + im * 16 + (quad << 2) + r;
                float v = acc[im][in][r];
                v = v > 0.f ? v : 0.f;
                y1c[((size_t)(b * P1 + m)) * HW + hw] = f2bf(v);
            }
        }
    }
}

// ---------------- dconv: y2t[n][m] = relu(conv3x3(y1sp, wdb)) ----------------
// operands SWAPPED in mfma so D col(lane&15)=m -> m-contiguous stores
__global__ __launch_bounds__(256) void dconv_kernel(const unsigned short* __restrict__ y1sp,
                                                    const unsigned short* __restrict__ wdb,
                                                    unsigned short* __restrict__ y2t) {
    __shared__ __align__(16) unsigned short As[128 * 64];
    __shared__ __align__(16) unsigned short Bs[128 * 64];
    const int m0 = blockIdx.x * 128;
    const int n0 = blockIdx.y * 128;
    const int t = threadIdx.x;
    const int lane = t & 63, wave = t >> 6;
    const int l15 = lane & 15, quad = lane >> 4;
    const int wm = wave & 1, wn = wave >> 1;
    const int grow = lane >> 3;
    const int gsw  = ((lane & 7) ^ grow) << 3;
    const unsigned short* Asrc[4];
    const unsigned short* Bsrc[4];
    int ldso[4];
#pragma unroll
    for (int j = 0; j < 4; ++j) {
        int q = wave * 4 + j;
        int row = (q << 3) + grow;
        Asrc[j] = wdb + (size_t)(m0 + row) * P1 + gsw;
        int n = n0 + row;
        int b = n / HW, hw = n - b * HW;
        int h = hw / WIMG, w = hw - h * WIMG;
        Bsrc[j] = y1sp + ((size_t)b * PADHW + h * PADW + w) * P1 + gsw;  // top-left of 3x3 window
        ldso[j] = q * 512;
    }
    const int coff0 = ((quad)     ^ (l15 & 7)) << 3;
    const int coff1 = ((quad + 4) ^ (l15 & 7)) << 3;

    accvec_t acc[4][4];
    const accvec_t zero = {0.f, 0.f, 0.f, 0.f};
#pragma unroll
    for (int i = 0; i < 4; ++i)
#pragma unroll
        for (int j = 0; j < 4; ++j) acc[i][j] = zero;

    for (int r = 0; r < 9; ++r) {
        const int kh = r / 3, kw = r - kh * 3;
        const size_t aoff = (size_t)r * (P1 * P2);
        const int taboff = (kh * PADW + kw) * P1;
        for (int k0 = 0; k0 < P1; k0 += 64) {
#pragma unroll
            for (int j = 0; j < 4; ++j) {
                GLDS16(Asrc[j] + aoff + k0, &As[ldso[j]]);
                GLDS16(Bsrc[j] + taboff + k0, &Bs[ldso[j]]);
            }
            __syncthreads();
            bfrag_t af[4], bfr[4];
#pragma unroll
            for (int i = 0; i < 4; ++i) {
                af[i]  = *(const bfrag_t*)&As[(wm * 64 + i * 16 + l15) * 64 + coff0];
                bfr[i] = *(const bfrag_t*)&Bs[(wn * 64 + i * 16 + l15) * 64 + coff0];
            }
#pragma unroll
            for (int im = 0; im < 4; ++im)
#pragma unroll
                for (int in = 0; in < 4; ++in)
                    acc[im][in] = __builtin_amdgcn_mfma_f32_16x16x32_bf16(bfr[in], af[im], acc[im][in], 0, 0, 0);
#pragma unroll
            for (int i = 0; i < 4; ++i) {
                af[i]  = *(const bfrag_t*)&As[(wm * 64 + i * 16 + l15) * 64 + coff1];
                bfr[i] = *(const bfrag_t*)&Bs[(wn * 64 + i * 16 + l15) * 64 + coff1];
            }
#pragma unroll
            for (int im = 0; im < 4; ++im)
#pragma unroll
                for (int in = 0; in < 4; ++in)
                    acc[im][in] = __builtin_amdgcn_mfma_f32_16x16x32_bf16(bfr[in], af[im], acc[im][in], 0, 0, 0);
            __syncthreads();
        }
    }
    // swapped D mapping: col(l15)=m, row(quad*4+r)=n
#pragma unroll
    for (int im = 0; im < 4; ++im) {
        const int m = m0 + wm * 64 + im * 16 + l15;
#pragma unroll
        for (int in = 0; in < 4; ++in) {
#pragma unroll
            for (int r = 0; r < 4; ++r) {
                const int n = n0 + wn * 64 + in * 16 + (quad << 2) + r;
                float v = acc[im][in][r];
                v = v > 0.f ? v : 0.f;
                y2t[(size_t)n * P2 + m] = f2bf(v);
            }
        }
    }
}

// ---------------- conv3 + residual add + relu ----------------
// K-loop proven; epilogue LDS-bounces the 128x128 fp32 tile in 4 chunks of
// 32x128 so out stores are 64B-contiguous (full 128B lines, no write-allocate)
// and res loads are 16B vectors prefetched one chunk ahead.
__global__ __launch_bounds__(256) void conv3_kernel(const unsigned short* __restrict__ y2t,
                                                    const unsigned short* __restrict__ w3b,
                                                    const unsigned short* __restrict__ res,
                                                    float* __restrict__ out) {
    __shared__ __align__(16) unsigned short SMEM[8448];   // 16.9KB: As(8KB)+Bs(8KB), aliased by Obuf
    unsigned short* As = SMEM;
    unsigned short* Bs = SMEM + 4096;
    float* Obuf = (float*)SMEM;                           // 32 rows x stride 132 floats

    const int m0 = blockIdx.x * 128;
    const int n0 = blockIdx.y * 128;
    const int t = threadIdx.x;
    const int lane = t & 63, wave = t >> 6;
    const int l15 = lane & 15, quad = lane >> 4;
    const int wm = wave & 1, wn = wave >> 1;
    const int srow = lane >> 2, c8 = (lane & 3) << 3;
    const int row0 = wave * 32 + srow, row1 = row0 + 16;

    const unsigned short* a0 = w3b + (size_t)(m0 + row0) * P2 + c8;
    const unsigned short* a1 = w3b + (size_t)(m0 + row1) * P2 + c8;
    const unsigned short* b0 = y2t + (size_t)(n0 + row0) * P2 + c8;
    const unsigned short* b1 = y2t + (size_t)(n0 + row1) * P2 + c8;
    unsigned short* Ad0 = &As[(wave * 2 + 0) * 512];
    unsigned short* Ad1 = &As[(wave * 2 + 1) * 512];
    unsigned short* Bd0 = &Bs[(wave * 2 + 0) * 512];
    unsigned short* Bd1 = &Bs[(wave * 2 + 1) * 512];

    // epilogue geometry: thread t -> (erow = t>>3, eseg = t&7); a 16-n segment
    // never crosses a batch image (784 % 16 == 0, n0 % 128 == 0).
    const int erow = t >> 3, eseg = t & 7;
    const int n_e  = n0 + eseg * 16;
    const int b_e  = n_e / HW;
    const int hw_e = n_e - b_e * HW;
    const size_t ebase0 = ((size_t)(b_e * P3 + m0 + erow)) * HW + hw_e;

    // prefetch chunk-0 residual (16 bf16 = 2 x 16B, 32B-aligned)
    usvec8 rsA = *(const usvec8*)&res[ebase0];
    usvec8 rsB = *(const usvec8*)&res[ebase0 + 8];

    accvec_t acc[4][4];
    const accvec_t zero = {0.f, 0.f, 0.f, 0.f};
#pragma unroll
    for (int i = 0; i < 4; ++i)
#pragma unroll
        for (int j = 0; j < 4; ++j) acc[i][j] = zero;

    for (int k0 = 0; k0 < P2; k0 += 32) {
        GLDS16(a0 + k0, Ad0);
        GLDS16(a1 + k0, Ad1);
        GLDS16(b0 + k0, Bd0);
        GLDS16(b1 + k0, Bd1);
        __syncthreads();
        bfrag_t af[4], bfr[4];
#pragma unroll
        for (int i = 0; i < 4; ++i) {
            af[i]  = *(const bfrag_t*)&As[(wm * 64 + i * 16 + l15) * 32 + (quad << 3)];
            bfr[i] = *(const bfrag_t*)&Bs[(wn * 64 + i * 16 + l15) * 32 + (quad << 3)];
        }
#pragma unroll
        for (int im = 0; im < 4; ++im)
#pragma unroll
            for (int in = 0; in < 4; ++in)
                acc[im][in] = __builtin_amdgcn_mfma_f32_16x16x32_bf16(af[im], bfr[in], acc[im][in], 0, 0, 0);
        __syncthreads();
    }

    // ---- LDS-bounce epilogue: 4 chunks of 32 m-rows x 128 n ----
#pragma unroll
    for (int c = 0; c < 4; ++c) {
        if (wm == (c >> 1)) {
            const int imb = (c & 1) * 2;
#pragma unroll
            for (int i2 = 0; i2 < 2; ++i2)
#pragma unroll
                for (int in = 0; in < 4; ++in)
#pragma unroll
                    for (int r = 0; r < 4; ++r)
                        Obuf[(i2 * 16 + (quad << 2) + r) * 132 + wn * 64 + in * 16 + l15] =
                            acc[imb + i2][in][r];
        }
        __syncthreads();
        usvec8 nxA = rsA, nxB = rsB;
        if (c < 3) {
            const size_t nb = ebase0 + (size_t)(c + 1) * 32 * HW;
            nxA = *(const usvec8*)&res[nb];
            nxB = *(const usvec8*)&res[nb + 8];
        }
        {
            const size_t base = ebase0 + (size_t)c * 32 * HW;
            float ov[16];
#pragma unroll
            for (int q4 = 0; q4 < 4; ++q4) {
                float4 v = *(const float4*)&Obuf[erow * 132 + eseg * 16 + q4 * 4];
                ov[q4 * 4 + 0] = v.x; ov[q4 * 4 + 1] = v.y;
                ov[q4 * 4 + 2] = v.z; ov[q4 * 4 + 3] = v.w;
            }
#pragma unroll
            for (int q4 = 0; q4 < 4; ++q4) {
                float4 w;
                float e0, e1, e2, e3;
                const int j = q4 * 4;
                e0 = ov[j + 0] + bf2f((unsigned short)(j + 0 < 8 ? rsA[j + 0] : rsB[j + 0 - 8]));
                e1 = ov[j + 1] + bf2f((unsigned short)(j + 1 < 8 ? rsA[j + 1] : rsB[j + 1 - 8]));
                e2 = ov[j + 2] + bf2f((unsigned short)(j + 2 < 8 ? rsA[j + 2] : rsB[j + 2 - 8]));
                e3 = ov[j + 3] + bf2f((unsigned short)(j + 3 < 8 ? rsA[j + 3] : rsB[j + 3 - 8]));
                w.x = e0 > 0.f ? e0 : 0.f;
                w.y = e1 > 0.f ? e1 : 0.f;
                w.z = e2 > 0.f ? e2 : 0.f;
                w.w = e3 > 0.f ? e3 : 0.f;
                *(float4*)&out[base + q4 * 4] = w;
            }
        }
        rsA = nxA; rsB = nxB;
        if (c < 3) __syncthreads();   // protect Obuf before next chunk's write phase
    }
}

extern "C" void kernel_launch(void* const* d_in, const int* in_sizes, int n_in,
                              void* d_out, int out_size, void* d_ws, size_t ws_size,
                              hipStream_t stream) {
    const float* x      = (const float*)d_in[0];
    const float* w1     = (const float*)d_in[1];
    const float* wd     = (const float*)d_in[2];
    const float* w3     = (const float*)d_in[3];
    const int*   perm_d = (const int*)d_in[4];
    const int*   perm_r = (const int*)d_in[5];
    float*       out    = (float*)d_out;

    char* ws = (char*)d_ws;
    unsigned short* y1sp  = (unsigned short*)(ws + 0);         // 14,745,600
    unsigned short* y2t   = (unsigned short*)(ws + 14745600);  // 12,845,056 (also y1c — dconv overwrites after shuffle_pad consumed it)
    int*            permT = (int*)(ws + 27590656);             //    802,816
    unsigned short* w1b   = (unsigned short*)(ws + 28393472);  //    524,288
    unsigned short* wdb   = (unsigned short*)(ws + 28917760);  //  1,179,648
    unsigned short* w3b   = (unsigned short*)(ws + 30097408);  //    524,288
    unsigned short* xt    = (unsigned short*)(ws + 30621696);  // 51,380,224 (also res — res_shuffle overwrites after conv1 consumed it)
    unsigned short* resb  = xt;
    unsigned short* y1c   = y2t;

    hipMemsetAsync(y1sp, 0, (size_t)BATCH * PADHW * P1 * sizeof(unsigned short), stream);
    permT_kernel<<<dim3(HW), dim3(256), 0, stream>>>(perm_d, permT);
    pack_weights_kernel<<<dim3(4352), dim3(256), 0, stream>>>(w1, wd, w3, w1b, wdb, w3b);
    transpose_x_kernel<<<dim3(CIN / 64, NFLAT / 64), dim3(256), 0, stream>>>(x, xt);

    conv1_kernel<<<dim3(P1 / 128, NFLAT / 128), dim3(256), 0, stream>>>(xt, w1b, y1c);
    res_shuffle_kernel<<<dim3(BATCH * CIN / 8), dim3(256), 0, stream>>>(x, perm_r, resb);
    shuffle_pad_kernel<<<dim3(BATCH * 8), dim3(256), 0, stream>>>(y1c, permT, y1sp);
    dconv_kernel<<<dim3(P2 / 128, NFLAT / 128), dim3(256), 0, stream>>>(y1sp, wdb, y2t);
    conv3_kernel<<<dim3(P3 / 128, NFLAT / 128), dim3(256), 0, stream>>>(y2t, w3b, resb, out);
}